// Round 13
// baseline (28.817 us; speedup 1.0000x reference)
//
#include <hip/hip_runtime.h>
#include <math.h>

// Problem constants: inputs (128, 64, 64, 32) fp32
#define BB 128
#define NN 64
#define DD 2048            // 64*32
#define NBLK 512           // 16 rows per block, 4 segments per batch
#define SEG 4

__device__ __forceinline__ float wave_reduce_sum_down(float v) {
    #pragma unroll
    for (int off = 32; off > 0; off >>= 1)
        v += __shfl_down(v, off, 64);
    return v;
}

__device__ __forceinline__ unsigned long long pack2(float a, float b) {
    return ((unsigned long long)__float_as_uint(b) << 32) |
            (unsigned long long)__float_as_uint(a);
}
__device__ __forceinline__ float2 unpack2(unsigned long long v) {
    return make_float2(__uint_as_float((unsigned)v),
                       __uint_as_float((unsigned)(v >> 32)));
}

// Fused: R10-winner streaming core (512 blk x 256 thr, wave owns 4 rows in
// registers, xor-butterfly sumsq, single HBM pass) + R8-proven fence-free
// finisher chain (relaxed agent atomics both sides, per-wave vmcnt(0) +
// __syncthreads before counter bumps; 4th arrival per batch combines the
// batch, 128th batch finisher does the fixed-order global tree).
__global__ __launch_bounds__(256) void fused_kernel(
        const float* __restrict__ x,
        float* __restrict__ vseg,        // [512][2048] via atomic u64 stores
        float* __restrict__ diag_seg,    // [512]
        double* __restrict__ partials,   // [128]
        unsigned* __restrict__ bcnt,     // [128] pre-zeroed by memset node
        unsigned* __restrict__ gcnt,     // [1]   pre-zeroed
        float* __restrict__ out) {
    const int u = blockIdx.x;
    const int b = u >> 2, s = u & 3;
    const int t = threadIdx.x;
    const int lane = t & 63, w = t >> 6;     // 4 waves

    // ---- streaming core: wave owns rows s*16 + w*4 .. +3, all in regs ----
    const float* xw = x + ((size_t)b * NN + s * 16 + w * 4) * DD;

    float4 acc[8];
    #pragma unroll
    for (int j = 0; j < 8; ++j) acc[j] = make_float4(0.f, 0.f, 0.f, 0.f);
    float diag = 0.f;                        // lane-uniform

    #pragma unroll
    for (int r = 0; r < 4; ++r) {
        const float4* p = reinterpret_cast<const float4*>(xw + (size_t)r * DD);
        float4 a[8];
        #pragma unroll
        for (int j = 0; j < 8; ++j) a[j] = p[lane + 64 * j];
        float ss = 0.f;
        #pragma unroll
        for (int j = 0; j < 8; ++j)
            ss += a[j].x * a[j].x + a[j].y * a[j].y
                + a[j].z * a[j].z + a[j].w * a[j].w;
        #pragma unroll
        for (int off = 1; off < 64; off <<= 1)   // butterfly: all lanes get sum
            ss += __shfl_xor(ss, off, 64);
        const float inv = 1.0f / fmaxf(sqrtf(ss), 1e-12f);
        diag += ss * inv * inv;                  // ||att_row||^2
        #pragma unroll
        for (int j = 0; j < 8; ++j) {
            acc[j].x = fmaf(a[j].x, inv, acc[j].x);
            acc[j].y = fmaf(a[j].y, inv, acc[j].y);
            acc[j].z = fmaf(a[j].z, inv, acc[j].z);
            acc[j].w = fmaf(a[j].w, inv, acc[j].w);
        }
    }

    // ---- cross-wave combine: [4][2048] floats = 32 KB LDS ----
    __shared__ float lds[4][DD];
    __shared__ float dl[4];
    __shared__ float red[4];
    __shared__ int flag;
    float4* lw = reinterpret_cast<float4*>(lds[w]);
    #pragma unroll
    for (int j = 0; j < 8; ++j) lw[lane + 64 * j] = acc[j];
    if (lane == 0) dl[w] = diag;
    __syncthreads();

    float4 o0 = make_float4(0.f, 0.f, 0.f, 0.f);
    float4 o1 = make_float4(0.f, 0.f, 0.f, 0.f);
    #pragma unroll
    for (int ww = 0; ww < 4; ++ww) {
        const float4* lr = reinterpret_cast<const float4*>(lds[ww]);
        float4 q0 = lr[t], q1 = lr[t + 256];
        o0.x += q0.x; o0.y += q0.y; o0.z += q0.z; o0.w += q0.w;
        o1.x += q1.x; o1.y += q1.y; o1.z += q1.z; o1.w += q1.w;
    }
    // publish segment vector at the coherence point (8B relaxed atomics)
    unsigned long long* dst =
        reinterpret_cast<unsigned long long*>(vseg + (size_t)u * DD);
    __hip_atomic_store(dst + 2 * t,       pack2(o0.x, o0.y),
                       __ATOMIC_RELAXED, __HIP_MEMORY_SCOPE_AGENT);
    __hip_atomic_store(dst + 2 * t + 1,   pack2(o0.z, o0.w),
                       __ATOMIC_RELAXED, __HIP_MEMORY_SCOPE_AGENT);
    __hip_atomic_store(dst + 2 * t + 512, pack2(o1.x, o1.y),
                       __ATOMIC_RELAXED, __HIP_MEMORY_SCOPE_AGENT);
    __hip_atomic_store(dst + 2 * t + 513, pack2(o1.z, o1.w),
                       __ATOMIC_RELAXED, __HIP_MEMORY_SCOPE_AGENT);
    if (t == 0)
        __hip_atomic_store(&diag_seg[u], dl[0] + dl[1] + dl[2] + dl[3],
                           __ATOMIC_RELAXED, __HIP_MEMORY_SCOPE_AGENT);
    // every wave drains its own stores, then block-wide rendezvous
    asm volatile("s_waitcnt vmcnt(0)" ::: "memory");
    __syncthreads();

    if (t == 0) {
        unsigned old = __hip_atomic_fetch_add(&bcnt[b], 1u,
                        __ATOMIC_RELAXED, __HIP_MEMORY_SCOPE_AGENT);
        flag = (old == 3u) ? 1 : 0;
    }
    __syncthreads();
    if (!flag) return;

    // ---- batch finisher (4th arrival): v_b = sum of 4 segment vectors ----
    {
        float4 c0 = make_float4(0.f, 0.f, 0.f, 0.f);
        float4 c1 = make_float4(0.f, 0.f, 0.f, 0.f);
        #pragma unroll
        for (int o = 0; o < SEG; ++o) {
            const unsigned long long* src =
                reinterpret_cast<const unsigned long long*>(
                    vseg + (size_t)(b * SEG + o) * DD);
            float2 l0 = unpack2(__hip_atomic_load(src + 2 * t,
                            __ATOMIC_RELAXED, __HIP_MEMORY_SCOPE_AGENT));
            float2 h0 = unpack2(__hip_atomic_load(src + 2 * t + 1,
                            __ATOMIC_RELAXED, __HIP_MEMORY_SCOPE_AGENT));
            float2 l1 = unpack2(__hip_atomic_load(src + 2 * t + 512,
                            __ATOMIC_RELAXED, __HIP_MEMORY_SCOPE_AGENT));
            float2 h1 = unpack2(__hip_atomic_load(src + 2 * t + 513,
                            __ATOMIC_RELAXED, __HIP_MEMORY_SCOPE_AGENT));
            c0.x += l0.x; c0.y += l0.y; c0.z += h0.x; c0.w += h0.y;
            c1.x += l1.x; c1.y += l1.y; c1.z += h1.x; c1.w += h1.y;
        }
        float p = c0.x * c0.x + c0.y * c0.y + c0.z * c0.z + c0.w * c0.w
                + c1.x * c1.x + c1.y * c1.y + c1.z * c1.z + c1.w * c1.w;
        p = wave_reduce_sum_down(p);
        if (lane == 0) red[w] = p;
    }
    __syncthreads();
    if (t == 0) {
        double sp = (double)red[0] + (double)red[1]
                  + (double)red[2] + (double)red[3];
        double dp = 0.0;
        #pragma unroll
        for (int o = 0; o < SEG; ++o)
            dp += (double)__hip_atomic_load(&diag_seg[b * SEG + o],
                        __ATOMIC_RELAXED, __HIP_MEMORY_SCOPE_AGENT);
        __hip_atomic_store(&partials[b], sp - dp,
                           __ATOMIC_RELAXED, __HIP_MEMORY_SCOPE_AGENT);
        asm volatile("s_waitcnt vmcnt(0)" ::: "memory");   // drain my store
        unsigned old = __hip_atomic_fetch_add(gcnt, 1u,
                        __ATOMIC_RELAXED, __HIP_MEMORY_SCOPE_AGENT);
        flag = (old == (unsigned)(BB - 1)) ? 1 : 0;
    }
    __syncthreads();
    if (!flag) return;

    // ---- global finisher: fixed-order tree over 128 batch partials ----
    __shared__ double sd[BB];
    if (t < BB)
        sd[t] = __hip_atomic_load(&partials[t],
                        __ATOMIC_RELAXED, __HIP_MEMORY_SCOPE_AGENT);
    __syncthreads();
    #pragma unroll
    for (int off = BB / 2; off > 0; off >>= 1) {
        if (t < off) sd[t] += sd[t + off];
        __syncthreads();
    }
    if (t == 0) out[0] = (float)(sd[0] / (double)BB);
}

extern "C" void kernel_launch(void* const* d_in, const int* in_sizes, int n_in,
                              void* d_out, int out_size, void* d_ws, size_t ws_size,
                              hipStream_t stream) {
    const float* x = (const float*)d_in[0];
    float* out = (float*)d_out;
    char* ws = (char*)d_ws;

    const size_t vbytes = (size_t)NBLK * DD * 4;           // 4 MB
    float* vseg       = (float*)ws;
    float* diag_seg   = (float*)(ws + vbytes);             // 2 KB
    double* partials  = (double*)(ws + vbytes + 2048);     // 1 KB
    unsigned* bcnt    = (unsigned*)(ws + vbytes + 2048 + 1024);  // 512 B
    unsigned* gcnt    = (unsigned*)(ws + vbytes + 2048 + 1024 + 512);

    hipMemsetAsync(bcnt, 0, 516, stream);                  // counters only
    fused_kernel<<<NBLK, 256, 0, stream>>>(x, vseg, diag_seg, partials,
                                           bcnt, gcnt, out);
}

// Round 14
// 21.998 us; speedup vs baseline: 1.3100x; 1.3100x over previous
//
#include <hip/hip_runtime.h>
#include <math.h>

// Problem constants: inputs (128, 64, 64, 32) fp32
#define BB 128
#define NN 64
#define DD 2048            // 64*32
#define NBLK1 512          // 16 rows per block, 4 segments per batch
#define SEG 4

__device__ __forceinline__ float wave_reduce_sum_down(float v) {
    #pragma unroll
    for (int off = 32; off > 0; off >>= 1)
        v += __shfl_down(v, off, 64);
    return v;
}

// K1: 512 blocks x 256 thr; wave owns 4 rows, ALL loaded up-front (32 float4
// in flight per lane). Sumsq partials for the 4 rows reduced by ONE packed
// xor-butterfly (4 independent shfls per step -> serial chain amortized 4x).
// Then inv per row, FMA the in-register rows into column accumulators.
// One 32 KB LDS combine. Block 0 zeroes the K2 counter.
__global__ __launch_bounds__(256) void stream_kernel(
        const float* __restrict__ x,
        float* __restrict__ vseg,        // [512][2048]
        float* __restrict__ diag_seg,    // [512]
        unsigned* __restrict__ counter) {
    const int u = blockIdx.x;
    const int b = u >> 2, s = u & 3;
    const int t = threadIdx.x;
    const int lane = t & 63, w = t >> 6;     // 4 waves

    if (u == 0 && t == 0) *counter = 0;      // visible to K2 at kernel boundary

    const float* xw = x + ((size_t)b * NN + s * 16 + w * 4) * DD;

    // ---- load all 4 rows up-front: 32 independent float4 per lane ----
    float4 a[4][8];
    #pragma unroll
    for (int r = 0; r < 4; ++r) {
        const float4* p = reinterpret_cast<const float4*>(xw + (size_t)r * DD);
        #pragma unroll
        for (int j = 0; j < 8; ++j) a[r][j] = p[lane + 64 * j];
    }

    // ---- per-lane sumsq partials for the 4 rows ----
    float ss[4];
    #pragma unroll
    for (int r = 0; r < 4; ++r) {
        float s4 = 0.f;
        #pragma unroll
        for (int j = 0; j < 8; ++j)
            s4 += a[r][j].x * a[r][j].x + a[r][j].y * a[r][j].y
                + a[r][j].z * a[r][j].z + a[r][j].w * a[r][j].w;
        ss[r] = s4;
    }

    // ---- ONE packed butterfly: 6 steps x 4 independent shfls ----
    #pragma unroll
    for (int off = 1; off < 64; off <<= 1) {
        float s0 = __shfl_xor(ss[0], off, 64);
        float s1 = __shfl_xor(ss[1], off, 64);
        float s2 = __shfl_xor(ss[2], off, 64);
        float s3 = __shfl_xor(ss[3], off, 64);
        ss[0] += s0; ss[1] += s1; ss[2] += s2; ss[3] += s3;
    }

    // ---- inv per row, diag, FMA rows into column accumulators ----
    float4 acc[8];
    #pragma unroll
    for (int j = 0; j < 8; ++j) acc[j] = make_float4(0.f, 0.f, 0.f, 0.f);
    float diag = 0.f;                        // lane-uniform
    #pragma unroll
    for (int r = 0; r < 4; ++r) {
        const float inv = 1.0f / fmaxf(sqrtf(ss[r]), 1e-12f);
        diag += ss[r] * inv * inv;           // ||att_row||^2
        #pragma unroll
        for (int j = 0; j < 8; ++j) {
            acc[j].x = fmaf(a[r][j].x, inv, acc[j].x);
            acc[j].y = fmaf(a[r][j].y, inv, acc[j].y);
            acc[j].z = fmaf(a[r][j].z, inv, acc[j].z);
            acc[j].w = fmaf(a[r][j].w, inv, acc[j].w);
        }
    }

    // ---- cross-wave combine: [4][2048] floats = 32 KB LDS ----
    __shared__ float lds[4][DD];
    __shared__ float dl[4];
    float4* lw = reinterpret_cast<float4*>(lds[w]);
    #pragma unroll
    for (int j = 0; j < 8; ++j) lw[lane + 64 * j] = acc[j];
    if (lane == 0) dl[w] = diag;
    __syncthreads();

    // thread t -> float4 indices t, t+256 (16B stride: conflict-free)
    float4 o0 = make_float4(0.f, 0.f, 0.f, 0.f);
    float4 o1 = make_float4(0.f, 0.f, 0.f, 0.f);
    #pragma unroll
    for (int ww = 0; ww < 4; ++ww) {
        const float4* lr = reinterpret_cast<const float4*>(lds[ww]);
        float4 p0 = lr[t], p1 = lr[t + 256];
        o0.x += p0.x; o0.y += p0.y; o0.z += p0.z; o0.w += p0.w;
        o1.x += p1.x; o1.y += p1.y; o1.z += p1.z; o1.w += p1.w;
    }
    float4* dst = reinterpret_cast<float4*>(vseg + (size_t)u * DD);
    dst[t] = o0;
    dst[t + 256] = o1;
    if (t == 0) diag_seg[u] = dl[0] + dl[1] + dl[2] + dl[3];
}

// K2: per-batch combine of SEG segment vectors + fence-free last-block tree.
// (byte-identical to R11's proven K2)
__global__ __launch_bounds__(256) void combine_kernel(
        const float* __restrict__ vseg,
        const float* __restrict__ diag_seg,
        double* __restrict__ partials,   // [128]
        unsigned* __restrict__ counter,  // zeroed by K1
        float* __restrict__ out) {
    const int b = blockIdx.x;
    const int t = threadIdx.x;
    const int lane = t & 63, wid = t >> 6;   // 4 waves

    __shared__ float red[4];
    __shared__ int flag;
    __shared__ double sd[BB];

    float4 c0 = make_float4(0.f, 0.f, 0.f, 0.f);
    float4 c1 = make_float4(0.f, 0.f, 0.f, 0.f);
    #pragma unroll
    for (int o = 0; o < SEG; ++o) {
        const float4* src = reinterpret_cast<const float4*>(
            vseg + (size_t)(b * SEG + o) * DD);
        float4 a0 = src[t], a1 = src[t + 256];
        c0.x += a0.x; c0.y += a0.y; c0.z += a0.z; c0.w += a0.w;
        c1.x += a1.x; c1.y += a1.y; c1.z += a1.z; c1.w += a1.w;
    }
    float p = c0.x * c0.x + c0.y * c0.y + c0.z * c0.z + c0.w * c0.w
            + c1.x * c1.x + c1.y * c1.y + c1.z * c1.z + c1.w * c1.w;
    p = wave_reduce_sum_down(p);
    if (lane == 0) red[wid] = p;
    __syncthreads();

    if (t == 0) {
        double sp = (double)red[0] + (double)red[1]
                  + (double)red[2] + (double)red[3];
        double dp = 0.0;
        #pragma unroll
        for (int o = 0; o < SEG; ++o) dp += (double)diag_seg[b * SEG + o];
        __hip_atomic_store(&partials[b], sp - dp,
                           __ATOMIC_RELAXED, __HIP_MEMORY_SCOPE_AGENT);
        asm volatile("s_waitcnt vmcnt(0)" ::: "memory");   // drain my store
        unsigned old = __hip_atomic_fetch_add(counter, 1u,
                        __ATOMIC_RELAXED, __HIP_MEMORY_SCOPE_AGENT);
        flag = (old == (unsigned)(BB - 1)) ? 1 : 0;
    }
    __syncthreads();
    if (!flag) return;

    if (t < BB)
        sd[t] = __hip_atomic_load(&partials[t],
                        __ATOMIC_RELAXED, __HIP_MEMORY_SCOPE_AGENT);
    __syncthreads();
    #pragma unroll
    for (int off = BB / 2; off > 0; off >>= 1) {
        if (t < off) sd[t] += sd[t + off];
        __syncthreads();
    }
    if (t == 0) out[0] = (float)(sd[0] / (double)BB);
}

extern "C" void kernel_launch(void* const* d_in, const int* in_sizes, int n_in,
                              void* d_out, int out_size, void* d_ws, size_t ws_size,
                              hipStream_t stream) {
    const float* x = (const float*)d_in[0];
    float* out = (float*)d_out;
    char* ws = (char*)d_ws;

    const size_t vbytes = (size_t)NBLK1 * DD * 4;          // 4 MB
    float* vseg       = (float*)ws;
    float* diag_seg   = (float*)(ws + vbytes);             // 2 KB
    double* partials  = (double*)(ws + vbytes + 2048);     // 1 KB
    unsigned* counter = (unsigned*)(ws + vbytes + 2048 + 1024);

    stream_kernel<<<NBLK1, 256, 0, stream>>>(x, vseg, diag_seg, counter);
    combine_kernel<<<BB, 256, 0, stream>>>(vseg, diag_seg, partials,
                                           counter, out);
}

// Round 15
// 21.512 us; speedup vs baseline: 1.3396x; 1.0226x over previous
//
#include <hip/hip_runtime.h>
#include <math.h>

// Problem constants: inputs (128, 64, 64, 32) fp32
#define BB 128
#define NN 64
#define DD 2048            // 64*32
#define NBLK1 512          // 16 rows per block, 4 segments per batch
#define SEG 4

typedef float f4 __attribute__((ext_vector_type(4)));

__device__ __forceinline__ float wave_reduce_sum_down(float v) {
    #pragma unroll
    for (int off = 32; off > 0; off >>= 1)
        v += __shfl_down(v, off, 64);
    return v;
}

// K1: 512 blocks x 256 thr; wave owns 4 rows, all loaded up-front with
// NON-TEMPORAL loads (single-touch 67 MB stream must not allocate in L2;
// keeps L2 free for vseg which K2 re-reads). Packed xor-butterfly sumsq,
// inv per row, FMA rows into column accumulators, 32 KB LDS combine.
// Block 0 zeroes the K2 counter (kernel boundary = visibility fence).
__global__ __launch_bounds__(256) void stream_kernel(
        const float* __restrict__ x,
        float* __restrict__ vseg,        // [512][2048]
        float* __restrict__ diag_seg,    // [512]
        unsigned* __restrict__ counter) {
    const int u = blockIdx.x;
    const int b = u >> 2, s = u & 3;
    const int t = threadIdx.x;
    const int lane = t & 63, w = t >> 6;     // 4 waves

    if (u == 0 && t == 0) *counter = 0;      // visible to K2 at kernel boundary

    const float* xw = x + ((size_t)b * NN + s * 16 + w * 4) * DD;

    // ---- load all 4 rows up-front: 32 independent NT float4 per lane ----
    f4 a[4][8];
    #pragma unroll
    for (int r = 0; r < 4; ++r) {
        const f4* p = reinterpret_cast<const f4*>(xw + (size_t)r * DD);
        #pragma unroll
        for (int j = 0; j < 8; ++j)
            a[r][j] = __builtin_nontemporal_load(&p[lane + 64 * j]);
    }

    // ---- per-lane sumsq partials for the 4 rows ----
    float ss[4];
    #pragma unroll
    for (int r = 0; r < 4; ++r) {
        float s4 = 0.f;
        #pragma unroll
        for (int j = 0; j < 8; ++j)
            s4 += a[r][j].x * a[r][j].x + a[r][j].y * a[r][j].y
                + a[r][j].z * a[r][j].z + a[r][j].w * a[r][j].w;
        ss[r] = s4;
    }

    // ---- ONE packed butterfly: 6 steps x 4 independent shfls ----
    #pragma unroll
    for (int off = 1; off < 64; off <<= 1) {
        float s0 = __shfl_xor(ss[0], off, 64);
        float s1 = __shfl_xor(ss[1], off, 64);
        float s2 = __shfl_xor(ss[2], off, 64);
        float s3 = __shfl_xor(ss[3], off, 64);
        ss[0] += s0; ss[1] += s1; ss[2] += s2; ss[3] += s3;
    }

    // ---- inv per row, diag, FMA rows into column accumulators ----
    f4 acc[8];
    #pragma unroll
    for (int j = 0; j < 8; ++j) acc[j] = (f4)(0.f);
    float diag = 0.f;                        // lane-uniform
    #pragma unroll
    for (int r = 0; r < 4; ++r) {
        const float inv = 1.0f / fmaxf(sqrtf(ss[r]), 1e-12f);
        diag += ss[r] * inv * inv;           // ||att_row||^2
        #pragma unroll
        for (int j = 0; j < 8; ++j) {
            acc[j].x = fmaf(a[r][j].x, inv, acc[j].x);
            acc[j].y = fmaf(a[r][j].y, inv, acc[j].y);
            acc[j].z = fmaf(a[r][j].z, inv, acc[j].z);
            acc[j].w = fmaf(a[r][j].w, inv, acc[j].w);
        }
    }

    // ---- cross-wave combine: [4][2048] floats = 32 KB LDS ----
    __shared__ float lds[4][DD];
    __shared__ float dl[4];
    f4* lw = reinterpret_cast<f4*>(lds[w]);
    #pragma unroll
    for (int j = 0; j < 8; ++j) lw[lane + 64 * j] = acc[j];
    if (lane == 0) dl[w] = diag;
    __syncthreads();

    // thread t -> float4 indices t, t+256 (16B stride: conflict-free)
    f4 o0 = (f4)(0.f);
    f4 o1 = (f4)(0.f);
    #pragma unroll
    for (int ww = 0; ww < 4; ++ww) {
        const f4* lr = reinterpret_cast<const f4*>(lds[ww]);
        f4 p0 = lr[t], p1 = lr[t + 256];
        o0 += p0;
        o1 += p1;
    }
    f4* dst = reinterpret_cast<f4*>(vseg + (size_t)u * DD);
    dst[t] = o0;                             // cacheable: K2 re-reads these
    dst[t + 256] = o1;
    if (t == 0) diag_seg[u] = dl[0] + dl[1] + dl[2] + dl[3];
}

// K2: per-batch combine of SEG segment vectors + fence-free last-block tree.
// (byte-identical to R11's proven K2)
__global__ __launch_bounds__(256) void combine_kernel(
        const float* __restrict__ vseg,
        const float* __restrict__ diag_seg,
        double* __restrict__ partials,   // [128]
        unsigned* __restrict__ counter,  // zeroed by K1
        float* __restrict__ out) {
    const int b = blockIdx.x;
    const int t = threadIdx.x;
    const int lane = t & 63, wid = t >> 6;   // 4 waves

    __shared__ float red[4];
    __shared__ int flag;
    __shared__ double sd[BB];

    float4 c0 = make_float4(0.f, 0.f, 0.f, 0.f);
    float4 c1 = make_float4(0.f, 0.f, 0.f, 0.f);
    #pragma unroll
    for (int o = 0; o < SEG; ++o) {
        const float4* src = reinterpret_cast<const float4*>(
            vseg + (size_t)(b * SEG + o) * DD);
        float4 a0 = src[t], a1 = src[t + 256];
        c0.x += a0.x; c0.y += a0.y; c0.z += a0.z; c0.w += a0.w;
        c1.x += a1.x; c1.y += a1.y; c1.z += a1.z; c1.w += a1.w;
    }
    float p = c0.x * c0.x + c0.y * c0.y + c0.z * c0.z + c0.w * c0.w
            + c1.x * c1.x + c1.y * c1.y + c1.z * c1.z + c1.w * c1.w;
    p = wave_reduce_sum_down(p);
    if (lane == 0) red[wid] = p;
    __syncthreads();

    if (t == 0) {
        double sp = (double)red[0] + (double)red[1]
                  + (double)red[2] + (double)red[3];
        double dp = 0.0;
        #pragma unroll
        for (int o = 0; o < SEG; ++o) dp += (double)diag_seg[b * SEG + o];
        __hip_atomic_store(&partials[b], sp - dp,
                           __ATOMIC_RELAXED, __HIP_MEMORY_SCOPE_AGENT);
        asm volatile("s_waitcnt vmcnt(0)" ::: "memory");   // drain my store
        unsigned old = __hip_atomic_fetch_add(counter, 1u,
                        __ATOMIC_RELAXED, __HIP_MEMORY_SCOPE_AGENT);
        flag = (old == (unsigned)(BB - 1)) ? 1 : 0;
    }
    __syncthreads();
    if (!flag) return;

    if (t < BB)
        sd[t] = __hip_atomic_load(&partials[t],
                        __ATOMIC_RELAXED, __HIP_MEMORY_SCOPE_AGENT);
    __syncthreads();
    #pragma unroll
    for (int off = BB / 2; off > 0; off >>= 1) {
        if (t < off) sd[t] += sd[t + off];
        __syncthreads();
    }
    if (t == 0) out[0] = (float)(sd[0] / (double)BB);
}

extern "C" void kernel_launch(void* const* d_in, const int* in_sizes, int n_in,
                              void* d_out, int out_size, void* d_ws, size_t ws_size,
                              hipStream_t stream) {
    const float* x = (const float*)d_in[0];
    float* out = (float*)d_out;
    char* ws = (char*)d_ws;

    const size_t vbytes = (size_t)NBLK1 * DD * 4;          // 4 MB
    float* vseg       = (float*)ws;
    float* diag_seg   = (float*)(ws + vbytes);             // 2 KB
    double* partials  = (double*)(ws + vbytes + 2048);     // 1 KB
    unsigned* counter = (unsigned*)(ws + vbytes + 2048 + 1024);

    stream_kernel<<<NBLK1, 256, 0, stream>>>(x, vseg, diag_seg, counter);
    combine_kernel<<<BB, 256, 0, stream>>>(vseg, diag_seg, partials,
                                           counter, out);
}

// Round 16
// 20.168 us; speedup vs baseline: 1.4288x; 1.0666x over previous
//
#include <hip/hip_runtime.h>
#include <math.h>

// Problem constants: inputs (128, 64, 64, 32) fp32
#define BB 128
#define NN 64
#define DD 2048            // 64*32
#define NBLK1 512          // 16 rows per block, 4 segments per batch
#define SEG 4

typedef float f4 __attribute__((ext_vector_type(4)));

__device__ __forceinline__ float wave_reduce_sum_down(float v) {
    #pragma unroll
    for (int off = 32; off > 0; off >>= 1)
        v += __shfl_down(v, off, 64);
    return v;
}

// K1: 512 blocks x 256 thr; wave owns 4 rows, all loaded up-front with
// NON-TEMPORAL loads (single-touch stream, no L2 allocate). Packed
// xor-butterfly sumsq, inv per row, FMA rows into column accumulators,
// 32 KB LDS combine. vseg/diag written with NON-TEMPORAL stores: no dirty
// L2 lines at kernel end -> no coherence writeback in the K1->K2 gap;
// K2 reads them from L3. Block 0 zeroes the K2 counter (kernel boundary
// = visibility fence).
__global__ __launch_bounds__(256) void stream_kernel(
        const float* __restrict__ x,
        float* __restrict__ vseg,        // [512][2048]
        float* __restrict__ diag_seg,    // [512]
        unsigned* __restrict__ counter) {
    const int u = blockIdx.x;
    const int b = u >> 2, s = u & 3;
    const int t = threadIdx.x;
    const int lane = t & 63, w = t >> 6;     // 4 waves

    if (u == 0 && t == 0) *counter = 0;      // visible to K2 at kernel boundary

    const float* xw = x + ((size_t)b * NN + s * 16 + w * 4) * DD;

    // ---- load all 4 rows up-front: 32 independent NT float4 per lane ----
    f4 a[4][8];
    #pragma unroll
    for (int r = 0; r < 4; ++r) {
        const f4* p = reinterpret_cast<const f4*>(xw + (size_t)r * DD);
        #pragma unroll
        for (int j = 0; j < 8; ++j)
            a[r][j] = __builtin_nontemporal_load(&p[lane + 64 * j]);
    }

    // ---- per-lane sumsq partials for the 4 rows ----
    float ss[4];
    #pragma unroll
    for (int r = 0; r < 4; ++r) {
        float s4 = 0.f;
        #pragma unroll
        for (int j = 0; j < 8; ++j)
            s4 += a[r][j].x * a[r][j].x + a[r][j].y * a[r][j].y
                + a[r][j].z * a[r][j].z + a[r][j].w * a[r][j].w;
        ss[r] = s4;
    }

    // ---- ONE packed butterfly: 6 steps x 4 independent shfls ----
    #pragma unroll
    for (int off = 1; off < 64; off <<= 1) {
        float s0 = __shfl_xor(ss[0], off, 64);
        float s1 = __shfl_xor(ss[1], off, 64);
        float s2 = __shfl_xor(ss[2], off, 64);
        float s3 = __shfl_xor(ss[3], off, 64);
        ss[0] += s0; ss[1] += s1; ss[2] += s2; ss[3] += s3;
    }

    // ---- inv per row, diag, FMA rows into column accumulators ----
    f4 acc[8];
    #pragma unroll
    for (int j = 0; j < 8; ++j) acc[j] = (f4)(0.f);
    float diag = 0.f;                        // lane-uniform
    #pragma unroll
    for (int r = 0; r < 4; ++r) {
        const float inv = 1.0f / fmaxf(sqrtf(ss[r]), 1e-12f);
        diag += ss[r] * inv * inv;           // ||att_row||^2
        #pragma unroll
        for (int j = 0; j < 8; ++j) {
            acc[j].x = fmaf(a[r][j].x, inv, acc[j].x);
            acc[j].y = fmaf(a[r][j].y, inv, acc[j].y);
            acc[j].z = fmaf(a[r][j].z, inv, acc[j].z);
            acc[j].w = fmaf(a[r][j].w, inv, acc[j].w);
        }
    }

    // ---- cross-wave combine: [4][2048] floats = 32 KB LDS ----
    __shared__ float lds[4][DD];
    __shared__ float dl[4];
    f4* lw = reinterpret_cast<f4*>(lds[w]);
    #pragma unroll
    for (int j = 0; j < 8; ++j) lw[lane + 64 * j] = acc[j];
    if (lane == 0) dl[w] = diag;
    __syncthreads();

    // thread t -> float4 indices t, t+256 (16B stride: conflict-free)
    f4 o0 = (f4)(0.f);
    f4 o1 = (f4)(0.f);
    #pragma unroll
    for (int ww = 0; ww < 4; ++ww) {
        const f4* lr = reinterpret_cast<const f4*>(lds[ww]);
        f4 p0 = lr[t], p1 = lr[t + 256];
        o0 += p0;
        o1 += p1;
    }
    f4* dst = reinterpret_cast<f4*>(vseg + (size_t)u * DD);
    __builtin_nontemporal_store(o0, &dst[t]);        // no dirty L2 lines
    __builtin_nontemporal_store(o1, &dst[t + 256]);
    if (t == 0)
        __builtin_nontemporal_store(dl[0] + dl[1] + dl[2] + dl[3],
                                    &diag_seg[u]);
}

// K2: per-batch combine of SEG segment vectors + fence-free last-block tree.
__global__ __launch_bounds__(256) void combine_kernel(
        const float* __restrict__ vseg,
        const float* __restrict__ diag_seg,
        double* __restrict__ partials,   // [128]
        unsigned* __restrict__ counter,  // zeroed by K1
        float* __restrict__ out) {
    const int b = blockIdx.x;
    const int t = threadIdx.x;
    const int lane = t & 63, wid = t >> 6;   // 4 waves

    __shared__ float red[4];
    __shared__ int flag;
    __shared__ double sd[BB];

    f4 c0 = (f4)(0.f);
    f4 c1 = (f4)(0.f);
    #pragma unroll
    for (int o = 0; o < SEG; ++o) {
        const f4* src = reinterpret_cast<const f4*>(
            vseg + (size_t)(b * SEG + o) * DD);
        f4 a0 = __builtin_nontemporal_load(&src[t]);       // single-touch
        f4 a1 = __builtin_nontemporal_load(&src[t + 256]);
        c0 += a0;
        c1 += a1;
    }
    float p = c0.x * c0.x + c0.y * c0.y + c0.z * c0.z + c0.w * c0.w
            + c1.x * c1.x + c1.y * c1.y + c1.z * c1.z + c1.w * c1.w;
    p = wave_reduce_sum_down(p);
    if (lane == 0) red[wid] = p;
    __syncthreads();

    if (t == 0) {
        double sp = (double)red[0] + (double)red[1]
                  + (double)red[2] + (double)red[3];
        double dp = 0.0;
        #pragma unroll
        for (int o = 0; o < SEG; ++o) dp += (double)diag_seg[b * SEG + o];
        __hip_atomic_store(&partials[b], sp - dp,
                           __ATOMIC_RELAXED, __HIP_MEMORY_SCOPE_AGENT);
        asm volatile("s_waitcnt vmcnt(0)" ::: "memory");   // drain my store
        unsigned old = __hip_atomic_fetch_add(counter, 1u,
                        __ATOMIC_RELAXED, __HIP_MEMORY_SCOPE_AGENT);
        flag = (old == (unsigned)(BB - 1)) ? 1 : 0;
    }
    __syncthreads();
    if (!flag) return;

    if (t < BB)
        sd[t] = __hip_atomic_load(&partials[t],
                        __ATOMIC_RELAXED, __HIP_MEMORY_SCOPE_AGENT);
    __syncthreads();
    #pragma unroll
    for (int off = BB / 2; off > 0; off >>= 1) {
        if (t < off) sd[t] += sd[t + off];
        __syncthreads();
    }
    if (t == 0) out[0] = (float)(sd[0] / (double)BB);
}

extern "C" void kernel_launch(void* const* d_in, const int* in_sizes, int n_in,
                              void* d_out, int out_size, void* d_ws, size_t ws_size,
                              hipStream_t stream) {
    const float* x = (const float*)d_in[0];
    float* out = (float*)d_out;
    char* ws = (char*)d_ws;

    const size_t vbytes = (size_t)NBLK1 * DD * 4;          // 4 MB
    float* vseg       = (float*)ws;
    float* diag_seg   = (float*)(ws + vbytes);             // 2 KB
    double* partials  = (double*)(ws + vbytes + 2048);     // 1 KB
    unsigned* counter = (unsigned*)(ws + vbytes + 2048 + 1024);

    stream_kernel<<<NBLK1, 256, 0, stream>>>(x, vseg, diag_seg, counter);
    combine_kernel<<<BB, 256, 0, stream>>>(vseg, diag_seg, partials,
                                           counter, out);
}